// Round 1
// baseline (163.010 us; speedup 1.0000x reference)
//
#include <hip/hip_runtime.h>
#include <stdint.h>
#include <math.h>
#include <limits.h>

#define THREADS 1024
#define NBINS   768
#define CAP     512
// bit-pattern base for x = 4.0f
#define BIN_BASE 0x40800000u
#define BIN_SHIFT 15

__device__ __forceinline__ uint32_t rotl32(uint32_t x, int r) {
  return (x << r) | (x >> (32 - r));
}

// JAX threefry2x32 with key (0, 42), partitionable-mode 32-bit output (x0 ^ x1).
__device__ uint32_t threefry_bits(uint32_t c0, uint32_t c1) {
  const uint32_t ks0 = 0u;
  const uint32_t ks1 = 42u;
  const uint32_t ks2 = 0x1BD11BDAu ^ ks0 ^ ks1;
  uint32_t x0 = c0 + ks0;
  uint32_t x1 = c1 + ks1;
#define TF_R(r) { x0 += x1; x1 = rotl32(x1, (r)); x1 ^= x0; }
  TF_R(13) TF_R(15) TF_R(26) TF_R(6)
  x0 += ks1; x1 += ks2 + 1u;
  TF_R(17) TF_R(29) TF_R(16) TF_R(24)
  x0 += ks2; x1 += ks0 + 2u;
  TF_R(13) TF_R(15) TF_R(26) TF_R(6)
  x0 += ks0; x1 += ks1 + 3u;
  TF_R(17) TF_R(29) TF_R(16) TF_R(24)
  x0 += ks1; x1 += ks2 + 4u;
  TF_R(13) TF_R(15) TF_R(26) TF_R(6)
  x0 += ks2; x1 += ks0 + 5u;
#undef TF_R
  return x0 ^ x1;
}

// Exact replication of jax.random.gumbel(f32): uniform(minval=tiny, maxval=1) then -log(-log(u)).
__device__ float jax_gumbel(uint64_t flat) {
  uint32_t bits = threefry_bits((uint32_t)(flat >> 32), (uint32_t)flat);
  uint32_t fb = (bits >> 9) | 0x3f800000u;
  float f = __uint_as_float(fb) - 1.0f;          // [0, 1-2^-23]
  const float tiny = 1.17549435e-38f;            // finfo(f32).tiny
  // (maxval - minval) rounds to 1.0f; floats*1 + tiny; max(tiny, .)
  float u = fmaxf(tiny, f + tiny);
  return -logf(-logf(u));
}

__global__ __launch_bounds__(THREADS) void sampler_kernel(
    const float* __restrict__ logits, const int* __restrict__ top_k,
    const float* __restrict__ top_p, const float* __restrict__ temperature,
    const int* __restrict__ do_greedy, int* __restrict__ out, int V) {
  const int b = blockIdx.x;
  const int tid = threadIdx.x;
  const float* row = logits + (size_t)b * (size_t)V;

  __shared__ uint32_t hist[NBINS];
  __shared__ uint32_t chunk[256];
  __shared__ uint32_t s_thr;
  __shared__ int s_cnt;
  __shared__ float cv[CAP];
  __shared__ int ci[CAP];

  for (int i = tid; i < NBINS; i += THREADS) hist[i] = 0u;
  if (tid == 0) s_cnt = 0;
  __syncthreads();

  // ---- pass 1: histogram of bit-patterns of x >= 4.0 ----
  const int V4 = V >> 2;
  const float4* row4 = (const float4*)row;
  auto dohist = [&](float x) {
    if (x >= 4.0f) {
      uint32_t bits = __float_as_uint(x);
      uint32_t bin = (bits - BIN_BASE) >> BIN_SHIFT;
      if (bin >= NBINS) bin = NBINS - 1;
      atomicAdd(&hist[bin], 1u);
    }
  };
  for (int j = tid; j < V4; j += THREADS) {
    float4 v = row4[j];
    dohist(v.x); dohist(v.y); dohist(v.z); dohist(v.w);
  }
  for (int j = (V4 << 2) + tid; j < V; j += THREADS) dohist(row[j]);
  __syncthreads();

  // ---- find bin containing rank-k (suffix scan from top) ----
  if (tid < 256) {
    int base = tid * 3;
    chunk[tid] = hist[base] + hist[base + 1] + hist[base + 2];
  }
  __syncthreads();
  if (tid == 0) {
    int k = top_k[b]; if (k < 1) k = 1;
    uint32_t cum = 0; int bstar = 0;
    for (int c = 255; c >= 0; --c) {
      uint32_t cs = chunk[c];
      if (cum + cs >= (uint32_t)k) {
        for (int bb = c * 3 + 2; bb >= c * 3; --bb) {
          cum += hist[bb];
          if (cum >= (uint32_t)k) { bstar = bb; break; }
        }
        break;
      }
      cum += cs;
    }
    s_thr = BIN_BASE + ((uint32_t)bstar << BIN_SHIFT);
  }
  __syncthreads();

  // ---- pass 2: collect candidates (positive floats: bit order == value order) ----
  const uint32_t thr = s_thr;
  auto collect = [&](float x, int idx) {
    uint32_t bits = __float_as_uint(x);
    if (bits >= thr && bits < 0x80000000u) {
      int pos = atomicAdd(&s_cnt, 1);
      if (pos < CAP) { cv[pos] = x; ci[pos] = idx; }
    }
  };
  for (int j = tid; j < V4; j += THREADS) {
    float4 v = row4[j];
    int base = j << 2;
    collect(v.x, base); collect(v.y, base + 1);
    collect(v.z, base + 2); collect(v.w, base + 3);
  }
  for (int j = (V4 << 2) + tid; j < V; j += THREADS) collect(row[j], j);
  __syncthreads();

  const int nc = min(s_cnt, CAP);
  for (int i = tid; i < CAP; i += THREADS)
    if (i >= nc) { cv[i] = -INFINITY; ci[i] = INT_MAX; }

  // ---- bitonic sort CAP elements: value desc, index asc (stable order) ----
  for (int size = 2; size <= CAP; size <<= 1) {
    for (int stride = size >> 1; stride > 0; stride >>= 1) {
      __syncthreads();
      if (tid < CAP / 2) {
        int t = tid;
        int i = (t << 1) - (t & (stride - 1));
        int j = i + stride;
        float vi = cv[i], vj = cv[j];
        int ii = ci[i], ij = ci[j];
        bool up = ((i & size) == 0);
        // "first" = larger value, tie -> smaller index
        bool jfirst = (vj > vi) || (vj == vi && ij < ii);
        bool ifirst = (vi > vj) || (vi == vj && ii < ij);
        if (up ? jfirst : ifirst) {
          cv[i] = vj; cv[j] = vi; ci[i] = ij; ci[j] = ii;
        }
      }
    }
  }
  __syncthreads();

  // ---- serial epilogue: exact reference math on <= ~64 survivors ----
  if (tid == 0) {
    if (nc == 0) { out[b] = 0; return; }
    int k = top_k[b]; if (k < 1) k = 1; if (k > nc) k = nc;
    float vkth = cv[k - 1];
    int m = k;
    while (m < nc && cv[m] >= vkth) ++m;   // value-based top-k keep set (ties included)

    float Mx = cv[0];
    // softmax denominator: sum of exp over keep set (all other row entries contribute exact 0.0f)
    float S = 0.0f;
    for (int j = m - 1; j >= 0; --j) S += expf(cv[j] - Mx);

    float ptp = top_p[b];
    float tmp = temperature[b];
    float c = 0.0f;
    float best = -INFINITY;
    int besti = INT_MAX;
    for (int j = 0; j < m; ++j) {
      float p = expf(cv[j] - Mx) / S;
      c += p;                               // cumsum in sorted-descending order
      if ((c - p) < ptp) {                  // reference: (cum - sorted_probs) < top_p, strict
        int gi = ci[j];
        float g = jax_gumbel((uint64_t)b * (uint64_t)V + (uint64_t)gi);
        float sc = cv[j] / tmp + g;
        if (sc > best || (sc == best && gi < besti)) { best = sc; besti = gi; }
      }
    }
    out[b] = (*do_greedy != 0) ? ci[0] : besti;
  }
}

extern "C" void kernel_launch(void* const* d_in, const int* in_sizes, int n_in,
                              void* d_out, int out_size, void* d_ws, size_t ws_size,
                              hipStream_t stream) {
  const float* logits      = (const float*)d_in[0];
  const int*   top_k       = (const int*)d_in[1];
  const float* top_p       = (const float*)d_in[2];
  const float* temperature = (const float*)d_in[3];
  const int*   do_greedy   = (const int*)d_in[4];
  int B = in_sizes[1];
  int V = in_sizes[0] / B;
  int* out = (int*)d_out;
  sampler_kernel<<<B, THREADS, 0, stream>>>(logits, top_k, top_p, temperature,
                                            do_greedy, out, V);
}